// Round 1
// baseline (2694.599 us; speedup 1.0000x reference)
//
#include <hip/hip_runtime.h>
#include <hip/hip_bf16.h>

// Problem constants
constexpr int Bs = 512;   // batch
constexpr int Ss = 256;   // seq len
constexpr int Is = 32;    // input dim
constexpr int Hs = 256;   // hidden
constexpr int G4 = 1024;  // 4*H
constexpr int Os = 24;    // output dim
constexpr int MB = 16;    // batches per block
constexpr int NBLK = Bs / MB;  // 32 blocks
constexpr int NTH = 512;       // 8 waves

typedef __attribute__((ext_vector_type(8))) short short8;
typedef __attribute__((ext_vector_type(4))) float f32x4;

#define DEV static __device__ __forceinline__

DEV short f2bf(float f) {
  __hip_bfloat16 h = __float2bfloat16(f);
  short s;
  __builtin_memcpy(&s, &h, 2);
  return s;
}

DEV float frcp(float x) { return __builtin_amdgcn_rcpf(x); }

DEV float tanh_fast(float x) {
  x = fminf(fmaxf(x, -15.f), 15.f);
  float u = __expf(2.f * x);
  return (u - 1.f) * frcp(u + 1.f);
}

DEV short8 ldg8(const short* p) { return *reinterpret_cast<const short8*>(p); }

// ---------------- prep kernels ----------------
// W_stream frag layout (bf16): idx = (((w*8+nt)*8+kt)*64 + l)*8 + j
//   n = l&15, kgrp = (l>>4)&3, g = nt&3, half = nt>>2
//   gate-row gr = g*256 + w*32 + half*16 + n ; k = kt*32 + kgrp*8 + j
//   value = Whr[gr][k] = W[gr][256+k] + R[gr][k]
__global__ void prep_wstream(const float* __restrict__ W, const float* __restrict__ R,
                             short* __restrict__ wst) {
  int tid = blockIdx.x * 256 + threadIdx.x;  // 262144 total
  int j  = tid & 7;
  int l  = (tid >> 3) & 63;
  int kt = (tid >> 9) & 7;
  int nt = (tid >> 12) & 7;
  int w  = tid >> 15;
  int n = l & 15, kg = (l >> 4) & 3;
  int g = nt & 3, half = (nt >> 2) & 1;
  int gr = g * 256 + w * 32 + half * 16 + n;
  int k  = kt * 32 + kg * 8 + j;
  float v = W[gr * 512 + 256 + k] + R[gr * 256 + k];
  wst[tid] = f2bf(v);
}

// Weff = Wx @ W_in  (1024 x 32), stored as B-frags: idx = ((w*8+nt)*64+l)*8+j
__global__ void prep_weff(const float* __restrict__ W, const float* __restrict__ W_in,
                          short* __restrict__ weff) {
  int tid = blockIdx.x * 256 + threadIdx.x;  // 32768 total
  int j  = tid & 7;
  int l  = (tid >> 3) & 63;
  int nt = (tid >> 9) & 7;
  int w  = tid >> 12;
  int n = l & 15, kg = (l >> 4) & 3;
  int g = nt & 3, half = (nt >> 2) & 1;
  int gr = g * 256 + w * 32 + half * 16 + n;
  int i  = kg * 8 + j;
  float acc = 0.f;
  for (int h = 0; h < Hs; ++h) acc += W[gr * 512 + h] * W_in[h * 32 + i];
  weff[tid] = f2bf(acc);
}

// beff[gr] = b[gr] + sum_h Wx[gr,h]*b_in[h]
__global__ void prep_beff(const float* __restrict__ W, const float* __restrict__ b,
                          const float* __restrict__ b_in, float* __restrict__ beff) {
  int gr = blockIdx.x * 256 + threadIdx.x;  // 1024
  float a = b[gr];
  for (int h = 0; h < Hs; ++h) a += W[gr * 512 + h] * b_in[h];
  beff[gr] = a;
}

// ---------------- main recurrent kernel ----------------
// Block = 16 batches. 8 waves; wave w owns hidden units [w*32, w*32+32) x 4 gates
// as 8 N-tiles: nt = half*4 + g  (g: 0=i,1=f,2=z,3=o).
// h exchanged via LDS (bf16, [batch][hidden], 16B-chunk XOR-swizzled, double buf).
__global__ __launch_bounds__(NTH) void slstm_main(
    const float* __restrict__ x,      // (512,256,32)
    const float* __restrict__ Wout,   // (24,256)
    const float* __restrict__ bout,   // (24)
    const short* __restrict__ Wst,    // bf16 frags, 262144
    const short* __restrict__ WeffF,  // bf16 frags, 32768
    const float* __restrict__ beff,   // 1024
    float* __restrict__ out)          // (512,24)
{
  __shared__ short lds[2 * 4096 + 2 * 512];  // h bufs (2x8KB) + x bufs (2x1KB)
  const int tid = threadIdx.x;
  const int w   = tid >> 6;
  const int l   = tid & 63;
  const int lg  = l >> 4;    // lane group 0..3
  const int n16 = l & 15;
  const int b0  = blockIdx.x * MB;

  // persistent weights: Weff B-frags in registers
  short8 weff[8];
  const short* wfb = WeffF + (w * 8) * 512 + l * 8;
#pragma unroll
  for (int nt = 0; nt < 8; ++nt) weff[nt] = ldg8(wfb + nt * 512);

  // per-lane biases be[half][g]
  float be[2][4];
#pragma unroll
  for (int half = 0; half < 2; ++half)
#pragma unroll
    for (int g = 0; g < 4; ++g)
      be[half][g] = beff[g * 256 + w * 32 + half * 16 + n16];

  // states: s = half*4 + r ; batch = lg*4 + r ; hidden = w*32 + half*16 + n16
  float cst[8], nst[8], mst[8], hst[8];
#pragma unroll
  for (int s = 0; s < 8; ++s) { cst[s] = 0.f; nst[s] = 0.f; mst[s] = 0.f; hst[s] = 0.f; }

  // zero h buf0 (4096 shorts)
  {
    short8 z = {0, 0, 0, 0, 0, 0, 0, 0};
    *reinterpret_cast<short8*>(&lds[tid * 8]) = z;
  }
  // preload x(t=0) into x buf0 (wave 0)
  if (w == 0) {
    const float* px = x + (size_t)(b0 + (l >> 2)) * (Ss * Is) + (l & 3) * 8;
    f32x4 a = *(const f32x4*)px;
    f32x4 b = *(const f32x4*)(px + 4);
    short8 v;
    v[0] = f2bf(a[0]); v[1] = f2bf(a[1]); v[2] = f2bf(a[2]); v[3] = f2bf(a[3]);
    v[4] = f2bf(b[0]); v[5] = f2bf(b[1]); v[6] = f2bf(b[2]); v[7] = f2bf(b[3]);
    int lp = (l >> 2) | ((l & 3) << 4);
    *reinterpret_cast<short8*>(&lds[8192 + lp * 8]) = v;
  }
  __syncthreads();

  const short* wsb = Wst + (size_t)(w * 64) * 512 + l * 8;  // frag(nt,kt) at + (nt*8+kt)*512
  const f32x4 zero4 = {0.f, 0.f, 0.f, 0.f};

  for (int t = 0; t < Ss; ++t) {
    const int pb = t & 1;

    // prefetch x(t+1) to regs (wave 0)
    f32x4 xr0 = zero4, xr1 = zero4;
    if (w == 0 && t + 1 < Ss) {
      const float* px = x + (size_t)(b0 + (l >> 2)) * (Ss * Is) + (t + 1) * Is + (l & 3) * 8;
      xr0 = *(const f32x4*)px;
      xr1 = *(const f32x4*)(px + 4);
    }

    // x-part: acc[nt] = xA * Weff[nt]
    short8 xa = *reinterpret_cast<const short8*>(&lds[8192 + pb * 512 + l * 8]);
    f32x4 acc[8];
#pragma unroll
    for (int nt = 0; nt < 8; ++nt)
      acc[nt] = __builtin_amdgcn_mfma_f32_16x16x32_bf16(xa, weff[nt], zero4, 0, 0, 0);

    // h-part: stream Whr frags from L2, double-buffered in regs
    short8 bwA[8], bwB[8];
#pragma unroll
    for (int nt = 0; nt < 8; ++nt) bwA[nt] = ldg8(wsb + (nt * 8 + 0) * 512);
#pragma unroll
    for (int kt = 0; kt < 8; ++kt) {
      if (kt < 7) {
        short8* nxt = ((kt & 1) == 0) ? bwB : bwA;
#pragma unroll
        for (int nt = 0; nt < 8; ++nt) nxt[nt] = ldg8(wsb + (nt * 8 + kt + 1) * 512);
      }
      const short8* cur = ((kt & 1) == 0) ? bwA : bwB;
      // A-frag of h: batch = n16, chunk c = kt*4+lg, XOR swizzle by batch
      short8 a = *reinterpret_cast<const short8*>(
          &lds[pb * 4096 + n16 * 256 + (((kt * 4 + lg) ^ n16) & 31) * 8]);
#pragma unroll
      for (int nt = 0; nt < 8; ++nt)
        acc[nt] = __builtin_amdgcn_mfma_f32_16x16x32_bf16(a, cur[nt], acc[nt], 0, 0, 0);
    }

    // elementwise gate math (lane-local) + write h_new (bf16) to other buffer
#pragma unroll
    for (int half = 0; half < 2; ++half) {
#pragma unroll
      for (int r = 0; r < 4; ++r) {
        const int s = half * 4 + r;
        float xi = acc[half * 4 + 0][r] + be[half][0];
        float xf = acc[half * 4 + 1][r] + be[half][1];
        float xz = acc[half * 4 + 2][r] + be[half][2];
        float xo = acc[half * 4 + 3][r] + be[half][3];
        float lf = -__logf(1.f + __expf(-xf));  // log sigmoid
        float mn = fmaxf(lf + mst[s], xi);
        float ip = __expf(xi - mn);
        float fp = __expf(lf + mst[s] - mn);
        float tz = tanh_fast(xz);
        float cn  = fp * cst[s] + ip * tz;
        float nn2 = fp * nst[s] + ip;
        cst[s] = cn; nst[s] = nn2; mst[s] = mn;
        float so = frcp(1.f + __expf(-xo));
        float hv = so * tanh_fast(cn * frcp(nn2));
        hst[s] = hv;
        int jj   = w * 32 + half * 16 + n16;
        int bidx = lg * 4 + r;
        int off  = (pb ^ 1) * 4096 + bidx * 256 + (((jj >> 3) ^ bidx) & 31) * 8 + (jj & 7);
        lds[off] = f2bf(hv);
      }
    }

    // stage x(t+1) into other x buffer (wave 0)
    if (w == 0 && t + 1 < Ss) {
      short8 v;
      v[0] = f2bf(xr0[0]); v[1] = f2bf(xr0[1]); v[2] = f2bf(xr0[2]); v[3] = f2bf(xr0[3]);
      v[4] = f2bf(xr1[0]); v[5] = f2bf(xr1[1]); v[6] = f2bf(xr1[2]); v[7] = f2bf(xr1[3]);
      int lp = (l >> 2) | ((l & 3) << 4);
      *reinterpret_cast<short8*>(&lds[8192 + (pb ^ 1) * 512 + lp * 8]) = v;
    }
    __syncthreads();
  }

  // ---------- epilogue: out = h @ Wout^T + bout, then LN over 24 ----------
  float* h32 = reinterpret_cast<float*>(lds);  // 16 x 256 f32 (reuses h bufs)
#pragma unroll
  for (int half = 0; half < 2; ++half)
#pragma unroll
    for (int r = 0; r < 4; ++r) {
      int s = half * 4 + r;
      int jj = w * 32 + half * 16 + n16;
      int bidx = lg * 4 + r;
      h32[bidx * 256 + jj] = hst[s];
    }
  __syncthreads();

  float* olds = reinterpret_cast<float*>(&lds[8192]);  // 16 x 24 f32
  if (tid < MB * Os) {
    int bi = tid / Os, o = tid % Os;
    const float* wrow = Wout + o * Hs;
    const float* hrow = h32 + bi * Hs;
    float acc = bout[o];
#pragma unroll 4
    for (int j = 0; j < Hs; j += 4) {
      f32x4 hv = *(const f32x4*)(hrow + j);
      f32x4 wv = *(const f32x4*)(wrow + j);
      acc += hv[0] * wv[0] + hv[1] * wv[1] + hv[2] * wv[2] + hv[3] * wv[3];
    }
    olds[bi * Os + o] = acc;
  }
  __syncthreads();

  if (tid < MB) {
    float mu = 0.f;
#pragma unroll
    for (int o = 0; o < Os; ++o) mu += olds[tid * Os + o];
    mu *= (1.f / Os);
    float var = 0.f;
#pragma unroll
    for (int o = 0; o < Os; ++o) { float d = olds[tid * Os + o] - mu; var += d * d; }
    var *= (1.f / Os);
    float inv = rsqrtf(var + 1e-5f);
    for (int o = 0; o < Os; ++o)
      out[(size_t)(b0 + tid) * Os + o] = (olds[tid * Os + o] - mu) * inv;
  }
}

// ---------------- launcher ----------------
extern "C" void kernel_launch(void* const* d_in, const int* in_sizes, int n_in,
                              void* d_out, int out_size, void* d_ws, size_t ws_size,
                              hipStream_t stream) {
  const float* x    = (const float*)d_in[0];
  const float* W_in = (const float*)d_in[1];
  const float* b_in = (const float*)d_in[2];
  const float* W    = (const float*)d_in[3];
  const float* R    = (const float*)d_in[4];
  const float* bb   = (const float*)d_in[5];
  const float* Wout = (const float*)d_in[6];
  const float* bout = (const float*)d_in[7];
  float* out = (float*)d_out;

  short* wst  = (short*)d_ws;       // 262144 shorts = 512KB
  short* weff = wst + 262144;       // 32768 shorts = 64KB
  float* beff = (float*)(weff + 32768);  // 1024 floats = 4KB

  prep_wstream<<<1024, 256, 0, stream>>>(W, R, wst);
  prep_weff<<<128, 256, 0, stream>>>(W, W_in, weff);
  prep_beff<<<4, 256, 0, stream>>>(W, bb, b_in, beff);
  slstm_main<<<NBLK, NTH, 0, stream>>>(x, Wout, bout, wst, weff, beff, out);
}

// Round 3
// 1438.816 us; speedup vs baseline: 1.8728x; 1.8728x over previous
//
#include <hip/hip_runtime.h>
#include <hip/hip_bf16.h>

// Problem constants
constexpr int Bs = 512;   // batch
constexpr int Ss = 256;   // seq len
constexpr int Is = 32;    // input dim
constexpr int Hs = 256;   // hidden
constexpr int Os = 24;    // output dim
constexpr int MB = 16;    // batches per block
constexpr int NBLK = Bs / MB;  // 32 blocks
constexpr int NTH = 512;       // 8 waves

typedef __attribute__((ext_vector_type(8))) short short8;
typedef __attribute__((ext_vector_type(4))) float f32x4;

#define DEV static __device__ __forceinline__

DEV short f2bf(float f) {
  __hip_bfloat16 h = __float2bfloat16(f);
  short s;
  __builtin_memcpy(&s, &h, 2);
  return s;
}

DEV float frcp(float x) { return __builtin_amdgcn_rcpf(x); }

DEV float tanh_fast(float x) {
  x = fminf(fmaxf(x, -15.f), 15.f);
  float u = __expf(2.f * x);
  return (u - 1.f) * frcp(u + 1.f);
}

DEV short8 ldg8(const short* p) { return *reinterpret_cast<const short8*>(p); }

DEV float xvf(uint2 v, int r) {
  unsigned wd = (r & 2) ? v.y : v.x;
  unsigned bits = ((r & 1) ? (wd >> 16) : (wd & 0xffffu)) << 16;
  float f;
  __builtin_memcpy(&f, &bits, 4);
  return f;
}

// ---------------- prep kernels ----------------
// W_stream frag layout (bf16): idx = (((w*8+nt)*8+kt)*64 + l)*8 + j
//   n = l&15, kgrp=(l>>4)&3, g=nt&3, half=nt>>2
//   gate-row gr = g*256 + w*32 + half*16 + n ; k = kt*32 + kgrp*8 + j
//   value = Whr[gr][k] = W[gr][256+k] + R[gr][k]
__global__ void prep_wstream(const float* __restrict__ W, const float* __restrict__ R,
                             short* __restrict__ wst) {
  int tid = blockIdx.x * 256 + threadIdx.x;  // 262144 total
  int j  = tid & 7;
  int l  = (tid >> 3) & 63;
  int kt = (tid >> 9) & 7;
  int nt = (tid >> 12) & 7;
  int w  = tid >> 15;
  int n = l & 15, kg = (l >> 4) & 3;
  int g = nt & 3, half = (nt >> 2) & 1;
  int gr = g * 256 + w * 32 + half * 16 + n;
  int k  = kt * 32 + kg * 8 + j;
  float v = W[gr * 512 + 256 + k] + R[gr * 256 + k];
  wst[tid] = f2bf(v);
}

// Weff = Wx @ W_in  (1024 x 32), stored as B-frags: idx = ((w*8+nt)*64+l)*8+j
__global__ void prep_weff(const float* __restrict__ W, const float* __restrict__ W_in,
                          short* __restrict__ weff) {
  int tid = blockIdx.x * 256 + threadIdx.x;  // 32768 total
  int j  = tid & 7;
  int l  = (tid >> 3) & 63;
  int nt = (tid >> 9) & 7;
  int w  = tid >> 12;
  int n = l & 15, kg = (l >> 4) & 3;
  int g = nt & 3, half = (nt >> 2) & 1;
  int gr = g * 256 + w * 32 + half * 16 + n;
  int i  = kg * 8 + j;
  float acc = 0.f;
  for (int h = 0; h < Hs; ++h) acc += W[gr * 512 + h] * W_in[h * 32 + i];
  weff[tid] = f2bf(acc);
}

// Bias frag: bf[(w*8+nt)*64 + l] = b[gr] + dot(W[gr, 0:256], b_in), gr from (w,nt,l&15)
__global__ void prep_bfrag(const float* __restrict__ W, const float* __restrict__ b,
                           const float* __restrict__ b_in, float* __restrict__ bf) {
  int tid = blockIdx.x * 256 + threadIdx.x;  // 4096
  int l = tid & 63, nt = (tid >> 6) & 7, w = tid >> 9;
  int g = nt & 3, half = (nt >> 2) & 1;
  int gr = g * 256 + w * 32 + half * 16 + (l & 15);
  float a = b[gr];
  for (int h = 0; h < Hs; ++h) a += W[gr * 512 + h] * b_in[h];
  bf[tid] = a;
}

// ---------------- xp chunk GEMM ----------------
// Computes xp[t][batch][gate] = x[t] @ Weff^T + beff for tc steps, stored as
// packed bf16 in per-lane C-frag order:
//   xps[ (tt*64 + w*8+nt)*256 + l*4 + r ] : (batch=(l>>4)*4+r, gate-col nt:l&15)
DEV void chunk_gemm(const float* __restrict__ x, const short* __restrict__ weffF,
                    const float* __restrict__ bfrag, short* __restrict__ xps,
                    int b0, int w, int l, int t0, int tc) {
  const int l15 = l & 15, lhi = l >> 4;
  float bv[8];
#pragma unroll
  for (int nt = 0; nt < 8; ++nt) bv[nt] = bfrag[(w * 8 + nt) * 64 + l];
  short8 wf[8];
#pragma unroll
  for (int nt = 0; nt < 8; ++nt) wf[nt] = ldg8(weffF + ((w * 8 + nt) * 64 + l) * 8);
  const float* px0 = x + (size_t)(b0 + l15) * (Ss * Is) + lhi * 8;
  for (int tt = 0; tt < tc; ++tt) {
    const float* px = px0 + (size_t)(t0 + tt) * Is;
    f32x4 a0 = *(const f32x4*)px;
    f32x4 a1 = *(const f32x4*)(px + 4);
    short8 xa;
#pragma unroll
    for (int j = 0; j < 4; ++j) { xa[j] = f2bf(a0[j]); xa[4 + j] = f2bf(a1[j]); }
    // NOTE: w*8 term was missing in R2 -> all 8 waves clobbered the same region.
    short* xo = xps + (size_t)tt * 16384 + (size_t)(w * 8) * 256 + l * 4;
#pragma unroll
    for (int nt = 0; nt < 8; ++nt) {
      f32x4 c = {bv[nt], bv[nt], bv[nt], bv[nt]};
      c = __builtin_amdgcn_mfma_f32_16x16x32_bf16(xa, wf[nt], c, 0, 0, 0);
      unsigned lo = ((unsigned)(unsigned short)f2bf(c[1]) << 16) | (unsigned short)f2bf(c[0]);
      unsigned hi = ((unsigned)(unsigned short)f2bf(c[3]) << 16) | (unsigned short)f2bf(c[2]);
      uint2 v; v.x = lo; v.y = hi;
      *reinterpret_cast<uint2*>(xo + (size_t)nt * 256) = v;
    }
  }
}

// ---------------- main recurrent kernel ----------------
// 32 blocks x 8 waves. Wave w owns hidden [w*32, w*32+32) x 4 gates.
// Whr resident: kt 0-5 in VGPRs (48 frags), kt 6-7 in LDS (16 frags/wave, 128 KB).
// h exchanged via LDS dbuf (16 KB). x-part: xp streamed from ws (packed bf16),
// or (INLINE_X) computed per step via in-register Weff MFMA.
template <bool INLINE_X>
__global__ __launch_bounds__(NTH, 2) void slstm_main(
    const float* __restrict__ x,
    const short* __restrict__ Wst,
    const short* __restrict__ WeffF,
    const float* __restrict__ Bfrag,
    const float* __restrict__ Wout,
    const float* __restrict__ bout,
    short* __restrict__ xp,
    float* __restrict__ out,
    int tc)
{
  extern __shared__ char smem[];
  short* hbuf = reinterpret_cast<short*>(smem);            // 2 * 4096 shorts = 16 KB
  short* wlds = reinterpret_cast<short*>(smem + 16384);    // 8*16*512 shorts = 128 KB

  const int tid = threadIdx.x;
  const int w   = tid >> 6;
  const int l   = tid & 63;
  const int lg  = l >> 4;
  const int n16 = l & 15;
  const int bb  = blockIdx.x;
  const int b0  = bb * MB;

  const short* wsb = Wst + (size_t)(w * 64) * 512 + l * 8;
  const f32x4 zero4 = {0.f, 0.f, 0.f, 0.f};

  // persistent weight frags kt 0..5 in registers
  short8 wreg[48];
#pragma unroll
  for (int kt = 0; kt < 6; ++kt)
#pragma unroll
    for (int nt = 0; nt < 8; ++nt)
      wreg[kt * 8 + nt] = ldg8(wsb + (nt * 8 + kt) * 512);

  // kt 6,7 frags staged to LDS
#pragma unroll
  for (int f = 0; f < 16; ++f) {
    int kt = 6 + (f >> 3), nt = f & 7;
    short8 v = ldg8(wsb + (nt * 8 + kt) * 512);
    *reinterpret_cast<short8*>(&wlds[(w * 16 + f) * 512 + l * 8]) = v;
  }

  // INLINE_X-only persistent data
  float bv[8];
  if constexpr (INLINE_X) {
#pragma unroll
    for (int nt = 0; nt < 8; ++nt) bv[nt] = Bfrag[(w * 8 + nt) * 64 + l];
  }

  // zero h buffer 0
  {
    short8 z = {0, 0, 0, 0, 0, 0, 0, 0};
    *reinterpret_cast<short8*>(&hbuf[tid * 8]) = z;
  }

  float cst[8], nst[8], mst[8];
#pragma unroll
  for (int s = 0; s < 8; ++s) { cst[s] = 0.f; nst[s] = 0.f; mst[s] = 0.f; }

  short* xp_blk = xp + (size_t)bb * tc * 16384;

  __syncthreads();

  for (int t0 = 0; t0 < Ss; t0 += tc) {
    if constexpr (!INLINE_X) {
      if (tc < Ss) {
        chunk_gemm(x, WeffF, Bfrag, xp_blk, b0, w, l, t0, tc);
        __syncthreads();
      }
    }
    for (int tt = 0; tt < tc; ++tt) {
      const int t = t0 + tt, pb = t & 1;

      // INLINE_X: load x A-frag + weff frags for this step
      short8 xa, wfx[8];
      if constexpr (INLINE_X) {
        const float* px = x + (size_t)(b0 + n16) * (Ss * Is) + (size_t)t * Is + lg * 8;
        f32x4 a0 = *(const f32x4*)px;
        f32x4 a1 = *(const f32x4*)(px + 4);
#pragma unroll
        for (int j = 0; j < 4; ++j) { xa[j] = f2bf(a0[j]); xa[4 + j] = f2bf(a1[j]); }
#pragma unroll
        for (int nt = 0; nt < 8; ++nt) wfx[nt] = ldg8(WeffF + ((w * 8 + nt) * 64 + l) * 8);
      }

#pragma unroll
      for (int half = 0; half < 2; ++half) {
        f32x4 acc[4];
        uint2 xv[4];
        if constexpr (!INLINE_X) {
          // xp loads (packed bf16, consumed only at gate math -> latency hidden)
          const short* xq = xp_blk + (size_t)tt * 16384 + (w * 8 + half * 4) * 256 + l * 4;
#pragma unroll
          for (int g = 0; g < 4; ++g) xv[g] = *reinterpret_cast<const uint2*>(xq + g * 256);
#pragma unroll
          for (int g = 0; g < 4; ++g) acc[g] = zero4;
        } else {
#pragma unroll
          for (int g = 0; g < 4; ++g) {
            float b = bv[half * 4 + g];
            f32x4 c = {b, b, b, b};
            acc[g] = __builtin_amdgcn_mfma_f32_16x16x32_bf16(xa, wfx[half * 4 + g], c, 0, 0, 0);
          }
        }
#pragma unroll
        for (int kt = 0; kt < 6; ++kt) {
          short8 ha = *reinterpret_cast<const short8*>(
              &hbuf[pb * 4096 + n16 * 256 + (((kt * 4 + lg) ^ n16) & 31) * 8]);
#pragma unroll
          for (int g = 0; g < 4; ++g)
            acc[g] = __builtin_amdgcn_mfma_f32_16x16x32_bf16(ha, wreg[kt * 8 + half * 4 + g], acc[g], 0, 0, 0);
        }
#pragma unroll
        for (int kt = 6; kt < 8; ++kt) {
          short8 ha = *reinterpret_cast<const short8*>(
              &hbuf[pb * 4096 + n16 * 256 + (((kt * 4 + lg) ^ n16) & 31) * 8]);
#pragma unroll
          for (int g = 0; g < 4; ++g) {
            short8 wf = *reinterpret_cast<const short8*>(
                &wlds[(w * 16 + (kt - 6) * 8 + half * 4 + g) * 512 + l * 8]);
            acc[g] = __builtin_amdgcn_mfma_f32_16x16x32_bf16(ha, wf, acc[g], 0, 0, 0);
          }
        }
        // gate math (lane-local) + h write to other buffer
#pragma unroll
        for (int r = 0; r < 4; ++r) {
          const int s = half * 4 + r;
          float xi = acc[0][r];
          float xf = acc[1][r];
          float xz = acc[2][r];
          float xo = acc[3][r];
          if constexpr (!INLINE_X) {
            xi += xvf(xv[0], r); xf += xvf(xv[1], r);
            xz += xvf(xv[2], r); xo += xvf(xv[3], r);
          }
          float lf = -__logf(1.f + __expf(-xf));  // log sigmoid
          float mn = fmaxf(lf + mst[s], xi);
          float ip = __expf(xi - mn);
          float fp = __expf(lf + mst[s] - mn);
          float tz = tanh_fast(xz);
          float cn  = fp * cst[s] + ip * tz;
          float nn2 = fp * nst[s] + ip;
          cst[s] = cn; nst[s] = nn2; mst[s] = mn;
          float so = frcp(1.f + __expf(-xo));
          float hv = so * tanh_fast(cn * frcp(nn2));
          int j  = w * 32 + half * 16 + n16;
          int bi = lg * 4 + r;
          hbuf[(pb ^ 1) * 4096 + bi * 256 + (((j >> 3) ^ bi) & 31) * 8 + (j & 7)] = f2bf(hv);
        }
      }
      __syncthreads();
    }
  }

  // ---------- epilogue ----------
  // final h (t=255 wrote buffer 0, bf16). Copy to f32 h32 (reuses weight LDS).
  float* h32 = reinterpret_cast<float*>(smem + 16384);  // 16 x 256 f32 = 16 KB
#pragma unroll
  for (int half = 0; half < 2; ++half)
#pragma unroll
    for (int r = 0; r < 4; ++r) {
      int j = w * 32 + half * 16 + n16, bi = lg * 4 + r;
      unsigned short u = (unsigned short)hbuf[bi * 256 + (((j >> 3) ^ bi) & 31) * 8 + (j & 7)];
      unsigned bits = (unsigned)u << 16;
      float hv;
      __builtin_memcpy(&hv, &bits, 4);
      h32[bi * 256 + j] = hv;
    }
  __syncthreads();

  float* olds = reinterpret_cast<float*>(smem + 32768);  // 16 x 24 f32
  if (tid < MB * Os) {
    int bi = tid / Os, o = tid % Os;
    const float* wrow = Wout + o * Hs;
    const float* hrow = h32 + bi * Hs;
    float acc = bout[o];
#pragma unroll 4
    for (int jj = 0; jj < Hs; jj += 4) {
      f32x4 hv = *(const f32x4*)(hrow + jj);
      f32x4 wv = *(const f32x4*)(wrow + jj);
      acc += hv[0] * wv[0] + hv[1] * wv[1] + hv[2] * wv[2] + hv[3] * wv[3];
    }
    olds[bi * Os + o] = acc;
  }
  __syncthreads();

  if (tid < MB) {
    float mu = 0.f;
#pragma unroll
    for (int o = 0; o < Os; ++o) mu += olds[tid * Os + o];
    mu *= (1.f / Os);
    float var = 0.f;
#pragma unroll
    for (int o = 0; o < Os; ++o) { float d = olds[tid * Os + o] - mu; var += d * d; }
    var *= (1.f / Os);
    float inv = rsqrtf(var + 1e-5f);
    for (int o = 0; o < Os; ++o)
      out[(size_t)(b0 + tid) * Os + o] = (olds[tid * Os + o] - mu) * inv;
  }
}

// ---------------- launcher ----------------
extern "C" void kernel_launch(void* const* d_in, const int* in_sizes, int n_in,
                              void* d_out, int out_size, void* d_ws, size_t ws_size,
                              hipStream_t stream) {
  const float* x    = (const float*)d_in[0];
  const float* W_in = (const float*)d_in[1];
  const float* b_in = (const float*)d_in[2];
  const float* W    = (const float*)d_in[3];
  const float* R    = (const float*)d_in[4];
  const float* bb_  = (const float*)d_in[5];
  const float* Wout = (const float*)d_in[6];
  const float* bout = (const float*)d_in[7];
  float* out = (float*)d_out;

  // workspace layout (bytes):
  //   [0, 524288)        Wst  bf16 frags
  //   [524288, 589824)   Weff bf16 frags
  //   [589824, 606208)   bias frags f32
  //   [655360, ...)      xp   packed bf16 (tc MB)
  short* wst   = (short*)d_ws;
  short* weff  = (short*)((char*)d_ws + 524288);
  float* bfrag = (float*)((char*)d_ws + 589824);
  short* xp    = (short*)((char*)d_ws + 655360);

  int tc = 16;  // xp chunk steps; tc MB of ws needed
  while (tc > 0 && (size_t)tc * 1048576 + 655360 > ws_size) tc >>= 1;

  prep_wstream<<<1024, 256, 0, stream>>>(W, R, wst);
  prep_weff<<<128, 256, 0, stream>>>(W, W_in, weff);
  prep_bfrag<<<16, 256, 0, stream>>>(W, bb_, b_in, bfrag);

  if (tc > 0) {
    hipFuncSetAttribute(reinterpret_cast<const void*>(slstm_main<false>),
                        hipFuncAttributeMaxDynamicSharedMemorySize, 147456);
    slstm_main<false><<<NBLK, NTH, 147456, stream>>>(x, wst, weff, bfrag, Wout, bout,
                                                     xp, out, tc);
  } else {
    hipFuncSetAttribute(reinterpret_cast<const void*>(slstm_main<true>),
                        hipFuncAttributeMaxDynamicSharedMemorySize, 147456);
    slstm_main<true><<<NBLK, NTH, 147456, stream>>>(x, wst, weff, bfrag, Wout, bout,
                                                    xp, out, Ss);
  }
}